// Round 1
// baseline (505.634 us; speedup 1.0000x reference)
//
#include <hip/hip_runtime.h>
#include <cmath>

#define KNBR 12
#define TOPK 13       // K+1, reference drops the closest (self)
#define NPT 1024      // points per batch
#define NB 32         // batches
#define IN_DIM 36     // K*3
#define HDIM 128
#define OUT_DIM 48    // 8*3*2
#define PTILE 16      // points per block in MLP stage

// ---------------- Stage A: KNN + local-frame gather ----------------
// grid: (NPT/64, NB), block: 64. One thread = one query point.
__global__ __launch_bounds__(64) void knn_kernel(const float* __restrict__ coords,
                                                 float* __restrict__ flat) {
    const int b = blockIdx.y;
    const int q = blockIdx.x * 64 + threadIdx.x;

    __shared__ float xs[NPT], ys[NPT], zs[NPT], sqs[NPT];
    const float* cb = coords + (size_t)b * NPT * 3;
    for (int i = threadIdx.x; i < NPT; i += 64) {
        float x = cb[3 * i + 0];
        float y = cb[3 * i + 1];
        float z = cb[3 * i + 2];
        xs[i] = x; ys[i] = y; zs[i] = z;
        sqs[i] = x * x + y * y + z * z;   // matches jnp.sum(c*c, -1)
    }
    __syncthreads();

    const float cx = xs[q], cy = ys[q], cz = zs[q];
    const float sq_q = sqs[q];

    // sorted ascending top-13 (distance, index); stable lowest-index ties,
    // matching jax.lax.top_k tie-breaking.
    float bestd[TOPK];
    int   besti[TOPK];
#pragma unroll
    for (int k = 0; k < TOPK; ++k) { bestd[k] = 1e30f; besti[k] = -1; }

    for (int j = 0; j < NPT; ++j) {
        // reference formula: sq_i + sq_j - 2*dot  (NOT dx^2+dy^2+dz^2)
        float dot = cx * xs[j] + cy * ys[j] + cz * zs[j];
        float d = sq_q + sqs[j] - 2.0f * dot;
        if (d < bestd[TOPK - 1]) {
            bestd[TOPK - 1] = d; besti[TOPK - 1] = j;
#pragma unroll
            for (int k = TOPK - 1; k > 0; --k) {
                if (bestd[k] < bestd[k - 1]) {   // strict <: equal keeps earlier index first
                    float td = bestd[k]; bestd[k] = bestd[k - 1]; bestd[k - 1] = td;
                    int   ti = besti[k]; besti[k] = besti[k - 1]; besti[k - 1] = ti;
                }
            }
        }
    }

    // drop bestd[0] (self: dist exactly 0 by formula symmetry — same drop-first
    // semantics as reference idx[:,:,1:])
    float* o = flat + (size_t)(b * NPT + q) * IN_DIM;
#pragma unroll
    for (int k = 1; k < TOPK; ++k) {
        int j = besti[k];
        o[(k - 1) * 3 + 0] = xs[j] - cx;
        o[(k - 1) * 3 + 1] = ys[j] - cy;
        o[(k - 1) * 3 + 2] = zs[j] - cz;
    }
}

// ---------------- Stage B: fused MLP + MADE + combine ----------------
// grid: 32768/PTILE blocks, 128 threads. Thread j owns neuron j; PTILE points.
// Note: x0 == 0 in the reference, so x0 @ (mw1*m1) vanishes -> mw1/m1 unused.
// Masks in closed form: m2[i][j] = (j%7 >= i%7); mo[h][o] = (o/6 > h%7).
__global__ __launch_bounds__(128) void mlp_kernel(
    const float* __restrict__ flat, const float* __restrict__ coords,
    const float* __restrict__ w_h1, const float* __restrict__ b_h1,
    const float* __restrict__ w_h2, const float* __restrict__ b_h2,
    const float* __restrict__ w_h3, const float* __restrict__ b_h3,
    const float* __restrict__ w_bp, const float* __restrict__ b_bp,
    const float* __restrict__ cw,  const float* __restrict__ mb1,
    const float* __restrict__ mw2, const float* __restrict__ mb2,
    const float* __restrict__ mwo, const float* __restrict__ mbo,
    float* __restrict__ out) {
    const int p0  = blockIdx.x * PTILE;
    const int tid = threadIdx.x;
    const int j   = tid;          // neuron index (0..127)

    __shared__ float x_lds[PTILE][IN_DIM];
    __shared__ float hA[PTILE][HDIM], hB[PTILE][HDIM];
    __shared__ float gA[PTILE][HDIM], gB[PTILE][HDIM];
    __shared__ float par_lds[PTILE][OUT_DIM], sh_lds[PTILE][OUT_DIM];

    for (int u = tid; u < PTILE * IN_DIM; u += 128)
        x_lds[u / IN_DIM][u % IN_DIM] = flat[(size_t)p0 * IN_DIM + u];
    __syncthreads();

    float acc_h[PTILE], acc_g[PTILE];

    // ---- layer 1 (h path) + MADE layer 1 (g path), input dim 36 ----
    {
        float bh = b_h1[j], bg = mb1[j];
#pragma unroll
        for (int p = 0; p < PTILE; ++p) { acc_h[p] = bh; acc_g[p] = bg; }
        for (int i = 0; i < IN_DIM; ++i) {
            float w1 = w_h1[i * HDIM + j];
            float wc = cw[i * HDIM + j];
#pragma unroll
            for (int p = 0; p < PTILE; ++p) {
                float x = x_lds[p][i];            // LDS broadcast (uniform addr)
                acc_h[p] = fmaf(x, w1, acc_h[p]);
                acc_g[p] = fmaf(x, wc, acc_g[p]);
            }
        }
#pragma unroll
        for (int p = 0; p < PTILE; ++p) {
            hA[p][j] = fmaxf(acc_h[p], 0.0f);
            gA[p][j] = tanhf(acc_g[p]);
        }
    }
    __syncthreads();

    // ---- layer 2 (h) + masked MADE layer 2 (g) ----
    {
        const int degj = j % 7;
        float bh = b_h2[j], bg = mb2[j];
#pragma unroll
        for (int p = 0; p < PTILE; ++p) { acc_h[p] = bh; acc_g[p] = bg; }
        for (int i = 0; i < HDIM; ++i) {
            float w2 = w_h2[i * HDIM + j];
            float wm = (degj >= (i % 7)) ? mw2[i * HDIM + j] : 0.0f;  // m2 mask
#pragma unroll
            for (int p = 0; p < PTILE; ++p) {
                acc_h[p] = fmaf(hA[p][i], w2, acc_h[p]);
                acc_g[p] = fmaf(gA[p][i], wm, acc_g[p]);
            }
        }
#pragma unroll
        for (int p = 0; p < PTILE; ++p) {
            hB[p][j] = fmaxf(acc_h[p], 0.0f);
            gB[p][j] = tanhf(acc_g[p]);
        }
    }
    __syncthreads();

    // ---- layer 3 (h only) ----
    {
        float bh = b_h3[j];
#pragma unroll
        for (int p = 0; p < PTILE; ++p) acc_h[p] = bh;
        for (int i = 0; i < HDIM; ++i) {
            float w3 = w_h3[i * HDIM + j];
#pragma unroll
            for (int p = 0; p < PTILE; ++p)
                acc_h[p] = fmaf(hB[p][i], w3, acc_h[p]);
        }
#pragma unroll
        for (int p = 0; p < PTILE; ++p) hA[p][j] = fmaxf(acc_h[p], 0.0f);
    }
    __syncthreads();

    // ---- output heads: wave0 -> params (48), wave1 -> shifts (48) ----
    {
        const int wv = tid >> 6;       // wave id (uniform branch)
        const int o  = tid & 63;
        if (o < OUT_DIM) {
            float acc[PTILE];
            if (wv == 0) {
                float bb = b_bp[o];
#pragma unroll
                for (int p = 0; p < PTILE; ++p) acc[p] = bb;
                for (int i = 0; i < HDIM; ++i) {
                    float w = w_bp[i * OUT_DIM + o];
#pragma unroll
                    for (int p = 0; p < PTILE; ++p)
                        acc[p] = fmaf(hA[p][i], w, acc[p]);
                }
#pragma unroll
                for (int p = 0; p < PTILE; ++p) par_lds[p][o] = acc[p];
            } else {
                const int dego = o / 6;   // deg_out-1
                float bb = mbo[o];
#pragma unroll
                for (int p = 0; p < PTILE; ++p) acc[p] = bb;
                for (int i = 0; i < HDIM; ++i) {
                    float w = (dego > (i % 7)) ? mwo[i * OUT_DIM + o] : 0.0f;  // mo mask
#pragma unroll
                    for (int p = 0; p < PTILE; ++p)
                        acc[p] = fmaf(gB[p][i], w, acc[p]);
                }
#pragma unroll
                for (int p = 0; p < PTILE; ++p) sh_lds[p][o] = acc[p];
            }
        }
    }
    __syncthreads();

    // ---- combine: pred = coord + (par+sh)[even], std = exp(0.5*(par+sh)[odd]) ----
    // out layout (B,N,8,3,2): flat offset within point = s*6 + d*2 + t == o
    for (int u = tid; u < PTILE * OUT_DIM; u += 128) {
        int p = u / OUT_DIM, o = u % OUT_DIM;
        float v = par_lds[p][o] + sh_lds[p][o];
        float r;
        if ((o & 1) == 0) {
            int d = (o % 6) >> 1;
            r = coords[(size_t)(p0 + p) * 3 + d] + v;
        } else {
            r = expf(0.5f * v);
        }
        out[(size_t)(p0 + p) * OUT_DIM + o] = r;
    }
}

extern "C" void kernel_launch(void* const* d_in, const int* in_sizes, int n_in,
                              void* d_out, int out_size, void* d_ws, size_t ws_size,
                              hipStream_t stream) {
    const float* coords = (const float*)d_in[0];
    const float* w_h1 = (const float*)d_in[1];
    const float* b_h1 = (const float*)d_in[2];
    const float* w_h2 = (const float*)d_in[3];
    const float* b_h2 = (const float*)d_in[4];
    const float* w_h3 = (const float*)d_in[5];
    const float* b_h3 = (const float*)d_in[6];
    const float* w_bp = (const float*)d_in[7];
    const float* b_bp = (const float*)d_in[8];
    const float* cw   = (const float*)d_in[9];
    // d_in[10] = mw1: dead (x0 == 0)
    const float* mb1  = (const float*)d_in[11];
    const float* mw2  = (const float*)d_in[12];
    const float* mb2  = (const float*)d_in[13];
    const float* mwo  = (const float*)d_in[14];
    const float* mbo  = (const float*)d_in[15];
    float* out = (float*)d_out;

    float* flat = (float*)d_ws;   // 32768 * 36 floats = 4.72 MB

    dim3 gA(NPT / 64, NB);
    knn_kernel<<<gA, 64, 0, stream>>>(coords, flat);

    const int nblocks = (NB * NPT) / PTILE;   // 2048
    mlp_kernel<<<nblocks, 128, 0, stream>>>(flat, coords,
                                            w_h1, b_h1, w_h2, b_h2, w_h3, b_h3,
                                            w_bp, b_bp, cw, mb1, mw2, mb2, mwo, mbo,
                                            out);
}